// Round 10
// baseline (319.779 us; speedup 1.0000x reference)
//
#include <hip/hip_runtime.h>
#include <stdint.h>

typedef __bf16 bf16;
typedef __bf16 bf16x8 __attribute__((ext_vector_type(8)));
typedef float f32x4 __attribute__((ext_vector_type(4)));

#define MFMA16(a, b, c) __builtin_amdgcn_mfma_f32_16x16x32_bf16((a), (b), (c), 0, 0, 0)

// async global->LDS DMA, 16B per lane. LDS dest must be wave-uniform; HW writes base + lane*16.
__device__ __forceinline__ void ldsdma16(const void* g, void* l) {
  __builtin_amdgcn_global_load_lds((const __attribute__((address_space(1))) void*)g,
                                   (__attribute__((address_space(3))) void*)l, 16, 0, 0);
}

// ---------------------------------------------------------------------------
// prep (merged): z==4 -> cast x fp32->bf16; z<4 -> transpose-cast W -> WT[n][k]
// ---------------------------------------------------------------------------
__global__ __launch_bounds__(256) void prep_kernel(const float* __restrict__ x,
                                                   const float* __restrict__ Wq,
                                                   const float* __restrict__ Wk,
                                                   const float* __restrict__ Wv,
                                                   const float* __restrict__ Wo,
                                                   bf16* __restrict__ xb,
                                                   bf16* __restrict__ WT) {
  __shared__ float tile[64][65];
  if (blockIdx.z == 4) {
    const int t = (blockIdx.y * 16 + blockIdx.x) * 256 + threadIdx.x;
#pragma unroll
    for (int i = 0; i < 16; ++i) {
      const int idx = (t + i * 65536) * 4;
      float4 v = *(const float4*)(x + idx);
      union { bf16 h[4]; uint2 u; } p;
      p.h[0] = (bf16)v.x; p.h[1] = (bf16)v.y; p.h[2] = (bf16)v.z; p.h[3] = (bf16)v.w;
      *(uint2*)(xb + idx) = p.u;
    }
    return;
  }
  const float* src = blockIdx.z == 0 ? Wq : blockIdx.z == 1 ? Wk : blockIdx.z == 2 ? Wv : Wo;
  bf16* dst = WT + (size_t)blockIdx.z * 1024 * 1024;
  const int k0 = blockIdx.y * 64, n0 = blockIdx.x * 64;
  const int rr = threadIdx.x >> 6, c = threadIdx.x & 63;
#pragma unroll
  for (int i = 0; i < 16; ++i) {
    int r = i * 4 + rr;
    tile[r][c] = src[(size_t)(k0 + r) * 1024 + n0 + c];
  }
  __syncthreads();
#pragma unroll
  for (int i = 0; i < 16; ++i) {
    int r = i * 4 + rr;
    dst[(size_t)(n0 + r) * 1024 + k0 + c] = (bf16)tile[c][r];
  }
}

// ===========================================================================
// qkv_gemm8: 256x256 tile, BK=64, 8 waves (2M x 4N), 8-phase counted-vmcnt
// schedule. LDS 128 KiB dynamic. launch_bounds(512) -> VGPR cap 256, no spill.
// XCD chunk swizzle (R9).
// ===========================================================================
__device__ __forceinline__ void stage_half(const bf16* __restrict__ src, int rowbase,
                                           int koff, char* lds, int bufq, int wave,
                                           int lane) {
#pragma unroll
  for (int i = 0; i < 2; ++i) {
    int chunk = i * 512 + wave * 64 + lane;  // 16B chunks, 8 per 64-col row
    int row = chunk >> 3;
    int cg = (chunk & 7) ^ (row & 7);        // pre-swizzled source column group
    ldsdma16(src + (size_t)(rowbase + row) * 1024 + koff + cg * 8,
             lds + bufq * 16384 + (i * 512 + wave * 64) * 16);
  }
}

__device__ __forceinline__ void ld_frag4(const bf16* lds, int bufq, int rbase, int quad,
                                         int l16, bf16x8 (&d)[4][2]) {
  const bf16x8* hb = (const bf16x8*)lds + bufq * 1024;
#pragma unroll
  for (int mf = 0; mf < 4; ++mf) {
    int row = rbase + mf * 16 + l16;
#pragma unroll
    for (int kk = 0; kk < 2; ++kk)
      d[mf][kk] = hb[row * 8 + ((kk * 4 + quad) ^ (row & 7))];
  }
}

__device__ __forceinline__ void ld_frag2(const bf16* lds, int bufq, int rbase, int quad,
                                         int l16, bf16x8 (&d)[2][2]) {
  const bf16x8* hb = (const bf16x8*)lds + bufq * 1024;
#pragma unroll
  for (int nf = 0; nf < 2; ++nf) {
    int row = rbase + nf * 16 + l16;
#pragma unroll
    for (int kk = 0; kk < 2; ++kk)
      d[nf][kk] = hb[row * 8 + ((kk * 4 + quad) ^ (row & 7))];
  }
}

template <int MQ, int NQ>
__device__ __forceinline__ void mma_quad(f32x4 (&acc)[8][4], const bf16x8 (&a)[4][2],
                                         const bf16x8 (&b)[2][2]) {
  __builtin_amdgcn_s_setprio(1);
#pragma unroll
  for (int mf = 0; mf < 4; ++mf)
#pragma unroll
    for (int nf = 0; nf < 2; ++nf)
#pragma unroll
      for (int kk = 0; kk < 2; ++kk)
        acc[MQ * 4 + mf][NQ * 2 + nf] =
            MFMA16(a[mf][kk], b[nf][kk], acc[MQ * 4 + mf][NQ * 2 + nf]);
  __builtin_amdgcn_s_setprio(0);
}

#define QBAR1() { __builtin_amdgcn_s_barrier(); \
                  asm volatile("s_waitcnt lgkmcnt(0)" ::: "memory"); }
#define QBAR2() { __builtin_amdgcn_s_barrier(); }

template <bool PRE>
__device__ __forceinline__ void qkv_iter(int k0, const bf16* __restrict__ xb,
                                         const bf16* __restrict__ BT, int m0, int n0,
                                         bf16* As, bf16* Bs, f32x4 (&acc)[8][4], int wave,
                                         int lane, int wm, int wn, int quad, int l16) {
  bf16x8 aF[4][2], b0F[2][2], b1F[2][2];
  // P1: quad (mq0,nq0) of tile a; stage A1(b)
  ld_frag4(As, 0, wm * 64, quad, l16, aF);
  ld_frag2(Bs, 0, wn * 32, quad, l16, b0F);
  stage_half(xb, m0 + 128, k0 + 64, (char*)As, 3, wave, lane);
  QBAR1(); mma_quad<0, 0>(acc, aF, b0F); QBAR2();
  // P2: (mq0,nq1), reuse aF; stage B0(b)
  ld_frag2(Bs, 1, wn * 32, quad, l16, b1F);
  stage_half(BT, n0, k0 + 64, (char*)Bs, 2, wave, lane);
  QBAR1(); mma_quad<0, 1>(acc, aF, b1F); QBAR2();
  // P3: (mq1,nq1); stage A0(a+2)
  ld_frag4(As, 1, wm * 64, quad, l16, aF);
  if (PRE) stage_half(xb, m0, k0 + 128, (char*)As, 0, wave, lane);
  QBAR1(); mma_quad<1, 1>(acc, aF, b1F); QBAR2();
  // P4: (mq1,nq0), reuse aF,b0F; stage B1(a+2); vmcnt gate for tile b
  if (PRE) stage_half(BT, n0 + 128, k0 + 128, (char*)Bs, 1, wave, lane);
  QBAR1(); mma_quad<1, 0>(acc, aF, b0F);
  if (PRE) { asm volatile("s_waitcnt vmcnt(4)" ::: "memory"); }
  else     { asm volatile("s_waitcnt vmcnt(0)" ::: "memory"); }
  QBAR2();
  // P5: tile b (mq0,nq0); stage A1(a+2)
  ld_frag4(As, 2, wm * 64, quad, l16, aF);
  ld_frag2(Bs, 2, wn * 32, quad, l16, b0F);
  if (PRE) stage_half(xb, m0 + 128, k0 + 128, (char*)As, 1, wave, lane);
  QBAR1(); mma_quad<0, 0>(acc, aF, b0F); QBAR2();
  // P6: (mq0,nq1); stage B0(a+2)
  ld_frag2(Bs, 3, wn * 32, quad, l16, b1F);
  if (PRE) stage_half(BT, n0, k0 + 128, (char*)Bs, 0, wave, lane);
  QBAR1(); mma_quad<0, 1>(acc, aF, b1F); QBAR2();
  // P7: (mq1,nq1); stage A0(b+2)
  ld_frag4(As, 3, wm * 64, quad, l16, aF);
  if (PRE) stage_half(xb, m0, k0 + 192, (char*)As, 2, wave, lane);
  QBAR1(); mma_quad<1, 1>(acc, aF, b1F); QBAR2();
  // P8: (mq1,nq0); stage B1(b+2); vmcnt gate for tile a+2
  if (PRE) stage_half(BT, n0 + 128, k0 + 192, (char*)Bs, 3, wave, lane);
  QBAR1(); mma_quad<1, 0>(acc, aF, b0F);
  if (PRE) { asm volatile("s_waitcnt vmcnt(4)" ::: "memory"); }
  QBAR2();
}

__global__ __launch_bounds__(512) void qkv_gemm8(const bf16* __restrict__ xb,
                                                 const bf16* __restrict__ WT,
                                                 const float* __restrict__ bq,
                                                 const float* __restrict__ bk,
                                                 const float* __restrict__ bv,
                                                 bf16* __restrict__ Qd,
                                                 bf16* __restrict__ Kd,
                                                 bf16* __restrict__ Vd) {
  extern __shared__ char smem_raw[];
  bf16* As = (bf16*)smem_raw;            // 64 KiB
  bf16* Bs = (bf16*)(smem_raw + 65536);  // 64 KiB

  const int tid = threadIdx.x, lane = tid & 63, wave = tid >> 6;
  const int wm = wave >> 2, wn = wave & 3;
  const int quad = lane >> 4, l16 = lane & 15;
  // XCD chunk swizzle: 192 blocks, 24 consecutive logical tiles per XCD
  const int ob = (blockIdx.x & 7) * 24 + (blockIdx.x >> 3);
  const int m0 = (ob / 12) * 256, n0 = (ob % 12) * 256;

  f32x4 acc[8][4];
  const f32x4 zero = {0.f, 0.f, 0.f, 0.f};
#pragma unroll
  for (int i = 0; i < 8; ++i)
#pragma unroll
    for (int j = 0; j < 4; ++j) acc[i][j] = zero;

  // prologue: tile0 fully + A0,B1 of tile1 (12 gloads); vmcnt(4) -> tile0 ready
  stage_half(xb, m0, 0, (char*)As, 0, wave, lane);
  stage_half(WT, n0, 0, (char*)Bs, 0, wave, lane);
  stage_half(xb, m0 + 128, 0, (char*)As, 1, wave, lane);
  stage_half(WT, n0 + 128, 0, (char*)Bs, 1, wave, lane);
  stage_half(xb, m0, 64, (char*)As, 2, wave, lane);
  stage_half(WT, n0 + 128, 64, (char*)Bs, 3, wave, lane);
  asm volatile("s_waitcnt vmcnt(4)" ::: "memory");
  __builtin_amdgcn_s_barrier();

  for (int j = 0; j < 7; ++j)
    qkv_iter<true>(j * 128, xb, WT, m0, n0, As, Bs, acc, wave, lane, wm, wn, quad, l16);
  qkv_iter<false>(896, xb, WT, m0, n0, As, Bs, acc, wave, lane, wm, wn, quad, l16);

  // epilogue: bias, fold softmax scale into Q, scatter to [B,H,S,HD]
#pragma unroll
  for (int MQ = 0; MQ < 2; ++MQ)
#pragma unroll
    for (int mf = 0; mf < 4; ++mf)
#pragma unroll
      for (int NQ = 0; NQ < 2; ++NQ)
#pragma unroll
        for (int nf = 0; nf < 2; ++nf) {
          const int n = n0 + NQ * 128 + wn * 32 + nf * 16 + l16;  // 0..3071
          const int sel = n >> 10, d = n & 1023;
          const float bias = (sel == 0 ? bq : sel == 1 ? bk : bv)[d];
          bf16* dst = (sel == 0 ? Qd : sel == 1 ? Kd : Vd);
          const float scl = (sel == 0) ? 0.125f : 1.f;
          const int h = d >> 6, hd = d & 63;
#pragma unroll
          for (int r = 0; r < 4; ++r) {
            const int token = m0 + MQ * 128 + wm * 64 + mf * 16 + quad * 4 + r;
            const int bb = token >> 11, s = token & 2047;
            const float v = (acc[MQ * 4 + mf][NQ * 2 + nf][r] + bias) * scl;
            dst[((((size_t)bb * 16 + h) * 2048 + s) << 6) + hd] = (bf16)v;
          }
        }
}

// ---------------------------------------------------------------------------
// Shared GEMM mainloop (m97 structure) for out_gemm, templated on NJ.
// ---------------------------------------------------------------------------
template <int NJ>
__device__ __forceinline__ void gemm_mainloop(const bf16* __restrict__ A,
                                              const bf16* __restrict__ BT, int K,
                                              int m0, int n0, bf16* As, bf16* Bs,
                                              f32x4 (&acc)[4][NJ]) {
  constexpr int BN = NJ * 32;
  const int tid = threadIdx.x;
  const int lane = tid & 63;
  const int wave = tid >> 6;
  const int wm = wave >> 1, wn = wave & 1;
  const int quad = lane >> 4, l16 = lane & 15;

  const f32x4 zero = {0.f, 0.f, 0.f, 0.f};
#pragma unroll
  for (int i = 0; i < 4; ++i)
#pragma unroll
    for (int j = 0; j < NJ; ++j) acc[i][j] = zero;

  for (int k0 = 0; k0 < K; k0 += 32) {
#pragma unroll
    for (int c = 0; c < 2; ++c) {  // A: 512 chunks
      int chunk = wave * 128 + c * 64 + lane;
      int row = chunk >> 2;
      int cg = (chunk & 3) ^ ((row >> 1) & 3);
      ldsdma16(A + (size_t)(m0 + row) * K + k0 + cg * 8,
               (char*)As + (size_t)(wave * 128 + c * 64) * 16);
    }
#pragma unroll
    for (int c = 0; c < BN / 64; ++c) {  // B: BN*4 chunks
      int chunk = wave * (BN / 64) * 64 + c * 64 + lane;
      int row = chunk >> 2;
      int cg = (chunk & 3) ^ ((row >> 1) & 3);
      ldsdma16(BT + (size_t)(n0 + row) * K + k0 + cg * 8,
               (char*)Bs + (size_t)(wave * (BN / 64) * 64 + c * 64) * 16);
    }
    __syncthreads();
    bf16x8 af[4], bfv[NJ];
#pragma unroll
    for (int i = 0; i < 4; ++i) {
      int ra = wm * 64 + i * 16 + l16;
      af[i] = ((const bf16x8*)As)[ra * 4 + (quad ^ ((ra >> 1) & 3))];
    }
#pragma unroll
    for (int j = 0; j < NJ; ++j) {
      int rb = wn * (BN / 2) + j * 16 + l16;
      bfv[j] = ((const bf16x8*)Bs)[rb * 4 + (quad ^ ((rb >> 1) & 3))];
    }
#pragma unroll
    for (int i = 0; i < 4; ++i)
#pragma unroll
      for (int j = 0; j < NJ; ++j) acc[i][j] = MFMA16(af[i], bfv[j], acc[i][j]);
    __syncthreads();
  }
}

// ---------------------------------------------------------------------------
// Sliding-window attention, phase-based (R1-verified best version), XCD swizzle.
// ---------------------------------------------------------------------------
template <int NT, int MODE>
__device__ __forceinline__ void attn_phase(const int start, const bf16* __restrict__ Kb,
                                           const bf16* __restrict__ Vb, bf16* Ks, bf16* Vt,
                                           bf16* Psw, const bf16x8 qa0, const bf16x8 qa1,
                                           const int i0, float (&mrow)[4], float (&lrow)[4],
                                           f32x4 (&oacc)[4]) {
  const int tid = threadIdx.x, lane = tid & 63, wave = tid >> 6;
  const int quad = lane >> 4, l16 = lane & 15;
  const f32x4 zero = {0.f, 0.f, 0.f, 0.f};

  __syncthreads();  // previous phase's Ks/Vt use done
#pragma unroll
  for (int c = 0; c < NT / 2; ++c) {
    int chunk = c * 256 + wave * 64 + lane;
    int row = chunk >> 3;
    int cg = (chunk & 7) ^ (row & 7);
    ldsdma16(Kb + (size_t)(start + row) * 64 + cg * 8,
             (char*)Ks + (size_t)(c * 256 + wave * 64) * 16);
  }
  if (NT == 8) {
    const int key = tid >> 1, hc = (tid & 1) * 32;
    const bf16* vp = Vb + (size_t)(start + key) * 64 + hc;
    bf16x8 v0 = ((const bf16x8*)vp)[0], v1 = ((const bf16x8*)vp)[1];
    bf16x8 v2 = ((const bf16x8*)vp)[2], v3 = ((const bf16x8*)vp)[3];
#pragma unroll
    for (int i = 0; i < 8; ++i) Vt[(hc + i) * 136 + key] = v0[i];
#pragma unroll
    for (int i = 0; i < 8; ++i) Vt[(hc + 8 + i) * 136 + key] = v1[i];
#pragma unroll
    for (int i = 0; i < 8; ++i) Vt[(hc + 16 + i) * 136 + key] = v2[i];
#pragma unroll
    for (int i = 0; i < 8; ++i) Vt[(hc + 24 + i) * 136 + key] = v3[i];
  } else {
    const int key = tid >> 2, hc = (tid & 3) * 16;
    const bf16* vp = Vb + (size_t)(start + key) * 64 + hc;
    bf16x8 v0 = ((const bf16x8*)vp)[0], v1 = ((const bf16x8*)vp)[1];
#pragma unroll
    for (int i = 0; i < 8; ++i) Vt[(hc + i) * 136 + key] = v0[i];
#pragma unroll
    for (int i = 0; i < 8; ++i) Vt[(hc + 8 + i) * 136 + key] = v1[i];
  }
  __syncthreads();

  f32x4 sc[NT];
  __builtin_amdgcn_s_setprio(1);
#pragma unroll
  for (int nt = 0; nt < NT; ++nt) {
    int key = nt * 16 + l16;
    bf16x8 kb0 = ((const bf16x8*)Ks)[key * 8 + ((0 * 4 + quad) ^ (key & 7))];
    bf16x8 kb1 = ((const bf16x8*)Ks)[key * 8 + ((1 * 4 + quad) ^ (key & 7))];
    f32x4 s = zero;
    s = MFMA16(qa0, kb0, s);
    s = MFMA16(qa1, kb1, s);
    sc[nt] = s;
  }
  __builtin_amdgcn_s_setprio(0);

  float alpha[4];
#pragma unroll
  for (int r = 0; r < 4; ++r) {
    const int i = i0 + r;
    float mx = -1e30f;
#pragma unroll
    for (int nt = 0; nt < NT; ++nt) {
      float s = sc[nt][r];
      if (MODE == 1) {
        const bool valid = (start + nt * 16 + l16 + 255 >= i);
        s = valid ? s : -1e30f;
        sc[nt][r] = s;
      } else if (MODE == 2) {
        const bool valid = (start + nt * 16 + l16 <= i);
        s = valid ? s : -1e30f;
        sc[nt][r] = s;
      }
      mx = fmaxf(mx, s);
    }
#pragma unroll
    for (int m = 8; m >= 1; m >>= 1) mx = fmaxf(mx, __shfl_xor(mx, m, 64));
    const float mnew = fmaxf(mrow[r], mx);
    alpha[r] = __expf(mrow[r] - mnew);
    mrow[r] = mnew;
    float rs = 0.f;
#pragma unroll
    for (int nt = 0; nt < NT; ++nt) {
      const float p = __expf(sc[nt][r] - mnew);
      sc[nt][r] = p;
      rs += p;
    }
#pragma unroll
    for (int m = 8; m >= 1; m >>= 1) rs += __shfl_xor(rs, m, 64);
    lrow[r] = lrow[r] * alpha[r] + rs;
  }

#pragma unroll
  for (int nt = 0; nt < NT; ++nt)
#pragma unroll
    for (int r = 0; r < 4; ++r)
      Psw[(quad * 4 + r) * 136 + nt * 16 + l16] = (bf16)sc[nt][r];
  asm volatile("s_waitcnt lgkmcnt(0)" ::: "memory");  // same-wave LDS RAW
  bf16x8 pa[NT / 2];
#pragma unroll
  for (int ks = 0; ks < NT / 2; ++ks)
    pa[ks] = ((const bf16x8*)Psw)[l16 * 17 + ks * 4 + quad];

  __builtin_amdgcn_s_setprio(1);
#pragma unroll
  for (int ht = 0; ht < 4; ++ht) {
    f32x4 o = oacc[ht];
#pragma unroll
    for (int r = 0; r < 4; ++r) o[r] *= alpha[r];
#pragma unroll
    for (int ks = 0; ks < NT / 2; ++ks) {
      bf16x8 vb = ((const bf16x8*)Vt)[(ht * 16 + l16) * 17 + ks * 4 + quad];
      o = MFMA16(pa[ks], vb, o);
    }
    oacc[ht] = o;
  }
  __builtin_amdgcn_s_setprio(0);
}

__global__ __launch_bounds__(256) void attn_kernel(const bf16* __restrict__ Q,
                                                   const bf16* __restrict__ K,
                                                   const bf16* __restrict__ V,
                                                   bf16* __restrict__ Ao) {
  __shared__ bf16 Ks[128 * 64] __attribute__((aligned(16)));
  __shared__ bf16 Vt[64 * 136] __attribute__((aligned(16)));
  __shared__ bf16 Ps[4][16 * 136] __attribute__((aligned(16)));

  const int tid = threadIdx.x, lane = tid & 63, wave = tid >> 6;
  const int quad = lane >> 4, l16 = lane & 15;
  const int ob = (blockIdx.x & 7) * 128 + (blockIdx.x >> 3);
  const int qt = ob & 31, h = (ob >> 5) & 15, b = ob >> 9;
  const int q0 = qt * 64;
  const size_t base = ((size_t)(b * 16 + h)) * 2048 * 64;
  const bf16* Qb = Q + base + (size_t)q0 * 64;
  const bf16* Kb = K + base;
  const bf16* Vb = V + base;

  const bf16* qrow = Qb + (size_t)(wave * 16 + l16) * 64 + quad * 8;
  const bf16x8 qa0 = *(const bf16x8*)qrow;
  const bf16x8 qa1 = *(const bf16x8*)(qrow + 32);

  float mrow[4], lrow[4];
  f32x4 oacc[4];
  const f32x4 zero = {0.f, 0.f, 0.f, 0.f};
#pragma unroll
  for (int r = 0; r < 4; ++r) { mrow[r] = -1e30f; lrow[r] = 0.f; }
#pragma unroll
  for (int t = 0; t < 4; ++t) oacc[t] = zero;

  const int i0 = q0 + wave * 16 + quad * 4;
  bf16* Psw = Ps[wave];

  if (q0 >= 256)
    attn_phase<8, 1>(q0 - 256, Kb, Vb, Ks, Vt, Psw, qa0, qa1, i0, mrow, lrow, oacc);
  else if (q0 == 192)
    attn_phase<4, 0>(0, Kb, Vb, Ks, Vt, Psw, qa0, qa1, i0, mrow, lrow, oacc);
  if (q0 >= 128)
    attn_phase<8, 0>(q0 - 128, Kb, Vb, Ks, Vt, Psw, qa0, qa1, i0, mrow, lrow, oacc);
  else if (q0 == 64)
    attn_phase<4, 0>(0, Kb, Vb, Ks, Vt, Psw, qa0, qa1, i0, mrow, lrow, oacc);
  attn_phase<4, 2>(q0, Kb, Vb, Ks, Vt, Psw, qa0, qa1, i0, mrow, lrow, oacc);

#pragma unroll
  for (int r = 0; r < 4; ++r) {
    const float inv = 1.f / lrow[r];
    const int row = q0 + wave * 16 + quad * 4 + r;
    const size_t outb = ((size_t)(b * 2048 + row)) * 1024 + h * 64;
#pragma unroll
    for (int ht = 0; ht < 4; ++ht)
      Ao[outb + ht * 16 + l16] = (bf16)(oacc[ht][r] * inv);
  }
}

// ---------------------------------------------------------------------------
// Output GEMM: Ao[4096,1024] @ Wo + bo -> fp32 out. BN=64 (512 blocks, 2/CU),
// XCD chunk swizzle.
// ---------------------------------------------------------------------------
__global__ __launch_bounds__(256) void out_gemm(const bf16* __restrict__ Ain,
                                                const bf16* __restrict__ WoT,
                                                const float* __restrict__ bo,
                                                float* __restrict__ out) {
  __shared__ bf16 As[128 * 32] __attribute__((aligned(16)));
  __shared__ bf16 Bs[64 * 32] __attribute__((aligned(16)));
  f32x4 acc[4][2];
  const int ob = (blockIdx.x & 7) * 64 + (blockIdx.x >> 3);
  const int m0 = (ob >> 4) * 128, n0 = (ob & 15) * 64;
  gemm_mainloop<2>(Ain, WoT, 1024, m0, n0, As, Bs, acc);

  const int lane = threadIdx.x & 63, wave = threadIdx.x >> 6;
  const int wm = wave >> 1, wn = wave & 1;
  const int quad = lane >> 4, l16 = lane & 15;
#pragma unroll
  for (int j = 0; j < 2; ++j) {
    const int n = n0 + wn * 32 + j * 16 + l16;
    const float bias = bo[n];
#pragma unroll
    for (int i = 0; i < 4; ++i) {
#pragma unroll
      for (int r = 0; r < 4; ++r) {
        const int token = m0 + wm * 64 + i * 16 + quad * 4 + r;
        out[(size_t)token * 1024 + n] = acc[i][j][r] + bias;
      }
    }
  }
}

// ---------------------------------------------------------------------------
// DIAGNOSTIC ROUND: qkv/attn/out each launched 3x (all idempotent).
// e2e = C + t_prep + 3*(t_qkv + t_attn + t_out); vs R9 anchor (168.2):
//   S = (e2e - 168.2)/2,  C + t_prep = 168.2 - S.  t_attn = 23.5 known (R7).
// Pre-committed decision: e2e < 270 -> kernel side near floor -> ROOFLINE.
//                         e2e >= 300 -> ~45us kernel headroom -> keep going.
// ---------------------------------------------------------------------------
extern "C" void kernel_launch(void* const* d_in, const int* in_sizes, int n_in,
                              void* d_out, int out_size, void* d_ws, size_t ws_size,
                              hipStream_t stream) {
  const float* x  = (const float*)d_in[0];
  const float* Wq = (const float*)d_in[1];
  const float* bq = (const float*)d_in[2];
  const float* Wk = (const float*)d_in[3];
  const float* bk = (const float*)d_in[4];
  const float* Wv = (const float*)d_in[5];
  const float* bv = (const float*)d_in[6];
  const float* Wo = (const float*)d_in[7];
  const float* bo = (const float*)d_in[8];
  float* out = (float*)d_out;

  char* ws = (char*)d_ws;
  bf16* xb = (bf16*)(ws);                      //  8 MB  x bf16
  bf16* WT = (bf16*)(ws + ((size_t)8 << 20));  //  8 MB  WqT|WkT|WvT|WoT bf16 [n][k]
  bf16* Qd = (bf16*)(ws + ((size_t)16 << 20)); //  8 MB  [B,H,S,HD]
  bf16* Kd = (bf16*)(ws + ((size_t)24 << 20)); //  8 MB
  bf16* Vd = (bf16*)(ws + ((size_t)32 << 20)); //  8 MB
  bf16* Ao = (bf16*)(ws + ((size_t)40 << 20)); //  8 MB  [B,S,DIM]

  (void)hipFuncSetAttribute((const void*)qkv_gemm8,
                            hipFuncAttributeMaxDynamicSharedMemorySize, 131072);

  prep_kernel<<<dim3(16, 16, 5), 256, 0, stream>>>(x, Wq, Wk, Wv, Wo, xb, WT);
  qkv_gemm8<<<dim3(192), 512, 131072, stream>>>(xb, WT, bq, bk, bv, Qd, Kd, Vd);
  qkv_gemm8<<<dim3(192), 512, 131072, stream>>>(xb, WT, bq, bk, bv, Qd, Kd, Vd);  // diag
  qkv_gemm8<<<dim3(192), 512, 131072, stream>>>(xb, WT, bq, bk, bv, Qd, Kd, Vd);  // diag
  attn_kernel<<<dim3(1024), 256, 0, stream>>>(Qd, Kd, Vd, Ao);
  attn_kernel<<<dim3(1024), 256, 0, stream>>>(Qd, Kd, Vd, Ao);  // diag
  attn_kernel<<<dim3(1024), 256, 0, stream>>>(Qd, Kd, Vd, Ao);  // diag
  out_gemm<<<dim3(512), 256, 0, stream>>>(Ao, WT + (size_t)3 * 1024 * 1024, bo, out);
  out_gemm<<<dim3(512), 256, 0, stream>>>(Ao, WT + (size_t)3 * 1024 * 1024, bo, out);  // diag
  out_gemm<<<dim3(512), 256, 0, stream>>>(Ao, WT + (size_t)3 * 1024 * 1024, bo, out);  // diag
}

// Round 11
// 163.444 us; speedup vs baseline: 1.9565x; 1.9565x over previous
//
#include <hip/hip_runtime.h>
#include <stdint.h>

typedef __bf16 bf16;
typedef __bf16 bf16x8 __attribute__((ext_vector_type(8)));
typedef float f32x4 __attribute__((ext_vector_type(4)));

#define MFMA16(a, b, c) __builtin_amdgcn_mfma_f32_16x16x32_bf16((a), (b), (c), 0, 0, 0)

// async global->LDS DMA, 16B per lane. LDS dest must be wave-uniform; HW writes base + lane*16.
__device__ __forceinline__ void ldsdma16(const void* g, void* l) {
  __builtin_amdgcn_global_load_lds((const __attribute__((address_space(1))) void*)g,
                                   (__attribute__((address_space(3))) void*)l, 16, 0, 0);
}

// ---------------------------------------------------------------------------
// prep (merged): z==4 -> cast x fp32->bf16; z<4 -> transpose-cast W -> WT[n][k]
// ---------------------------------------------------------------------------
__global__ __launch_bounds__(256) void prep_kernel(const float* __restrict__ x,
                                                   const float* __restrict__ Wq,
                                                   const float* __restrict__ Wk,
                                                   const float* __restrict__ Wv,
                                                   const float* __restrict__ Wo,
                                                   bf16* __restrict__ xb,
                                                   bf16* __restrict__ WT) {
  __shared__ float tile[64][65];
  if (blockIdx.z == 4) {
    const int t = (blockIdx.y * 16 + blockIdx.x) * 256 + threadIdx.x;
#pragma unroll
    for (int i = 0; i < 16; ++i) {
      const int idx = (t + i * 65536) * 4;
      float4 v = *(const float4*)(x + idx);
      union { bf16 h[4]; uint2 u; } p;
      p.h[0] = (bf16)v.x; p.h[1] = (bf16)v.y; p.h[2] = (bf16)v.z; p.h[3] = (bf16)v.w;
      *(uint2*)(xb + idx) = p.u;
    }
    return;
  }
  const float* src = blockIdx.z == 0 ? Wq : blockIdx.z == 1 ? Wk : blockIdx.z == 2 ? Wv : Wo;
  bf16* dst = WT + (size_t)blockIdx.z * 1024 * 1024;
  const int k0 = blockIdx.y * 64, n0 = blockIdx.x * 64;
  const int rr = threadIdx.x >> 6, c = threadIdx.x & 63;
#pragma unroll
  for (int i = 0; i < 16; ++i) {
    int r = i * 4 + rr;
    tile[r][c] = src[(size_t)(k0 + r) * 1024 + n0 + c];
  }
  __syncthreads();
#pragma unroll
  for (int i = 0; i < 16; ++i) {
    int r = i * 4 + rr;
    dst[(size_t)(n0 + r) * 1024 + k0 + c] = (bf16)tile[c][r];
  }
}

// ===========================================================================
// qkv_gemm8: 256x256 tile, BK=64, 8 waves (2M x 4N), 8-phase counted-vmcnt
// schedule. LDS 128 KiB dynamic. launch_bounds(512) -> VGPR cap 256, no spill.
// XCD chunk swizzle (R9). Unchanged from the 168.2us anchor.
// ===========================================================================
__device__ __forceinline__ void stage_half(const bf16* __restrict__ src, int rowbase,
                                           int koff, char* lds, int bufq, int wave,
                                           int lane) {
#pragma unroll
  for (int i = 0; i < 2; ++i) {
    int chunk = i * 512 + wave * 64 + lane;  // 16B chunks, 8 per 64-col row
    int row = chunk >> 3;
    int cg = (chunk & 7) ^ (row & 7);        // pre-swizzled source column group
    ldsdma16(src + (size_t)(rowbase + row) * 1024 + koff + cg * 8,
             lds + bufq * 16384 + (i * 512 + wave * 64) * 16);
  }
}

__device__ __forceinline__ void ld_frag4(const bf16* lds, int bufq, int rbase, int quad,
                                         int l16, bf16x8 (&d)[4][2]) {
  const bf16x8* hb = (const bf16x8*)lds + bufq * 1024;
#pragma unroll
  for (int mf = 0; mf < 4; ++mf) {
    int row = rbase + mf * 16 + l16;
#pragma unroll
    for (int kk = 0; kk < 2; ++kk)
      d[mf][kk] = hb[row * 8 + ((kk * 4 + quad) ^ (row & 7))];
  }
}

__device__ __forceinline__ void ld_frag2(const bf16* lds, int bufq, int rbase, int quad,
                                         int l16, bf16x8 (&d)[2][2]) {
  const bf16x8* hb = (const bf16x8*)lds + bufq * 1024;
#pragma unroll
  for (int nf = 0; nf < 2; ++nf) {
    int row = rbase + nf * 16 + l16;
#pragma unroll
    for (int kk = 0; kk < 2; ++kk)
      d[nf][kk] = hb[row * 8 + ((kk * 4 + quad) ^ (row & 7))];
  }
}

template <int MQ, int NQ>
__device__ __forceinline__ void mma_quad(f32x4 (&acc)[8][4], const bf16x8 (&a)[4][2],
                                         const bf16x8 (&b)[2][2]) {
  __builtin_amdgcn_s_setprio(1);
#pragma unroll
  for (int mf = 0; mf < 4; ++mf)
#pragma unroll
    for (int nf = 0; nf < 2; ++nf)
#pragma unroll
      for (int kk = 0; kk < 2; ++kk)
        acc[MQ * 4 + mf][NQ * 2 + nf] =
            MFMA16(a[mf][kk], b[nf][kk], acc[MQ * 4 + mf][NQ * 2 + nf]);
  __builtin_amdgcn_s_setprio(0);
}

#define QBAR1() { __builtin_amdgcn_s_barrier(); \
                  asm volatile("s_waitcnt lgkmcnt(0)" ::: "memory"); }
#define QBAR2() { __builtin_amdgcn_s_barrier(); }

template <bool PRE>
__device__ __forceinline__ void qkv_iter(int k0, const bf16* __restrict__ xb,
                                         const bf16* __restrict__ BT, int m0, int n0,
                                         bf16* As, bf16* Bs, f32x4 (&acc)[8][4], int wave,
                                         int lane, int wm, int wn, int quad, int l16) {
  bf16x8 aF[4][2], b0F[2][2], b1F[2][2];
  // P1: quad (mq0,nq0) of tile a; stage A1(b)
  ld_frag4(As, 0, wm * 64, quad, l16, aF);
  ld_frag2(Bs, 0, wn * 32, quad, l16, b0F);
  stage_half(xb, m0 + 128, k0 + 64, (char*)As, 3, wave, lane);
  QBAR1(); mma_quad<0, 0>(acc, aF, b0F); QBAR2();
  // P2: (mq0,nq1), reuse aF; stage B0(b)
  ld_frag2(Bs, 1, wn * 32, quad, l16, b1F);
  stage_half(BT, n0, k0 + 64, (char*)Bs, 2, wave, lane);
  QBAR1(); mma_quad<0, 1>(acc, aF, b1F); QBAR2();
  // P3: (mq1,nq1); stage A0(a+2)
  ld_frag4(As, 1, wm * 64, quad, l16, aF);
  if (PRE) stage_half(xb, m0, k0 + 128, (char*)As, 0, wave, lane);
  QBAR1(); mma_quad<1, 1>(acc, aF, b1F); QBAR2();
  // P4: (mq1,nq0), reuse aF,b0F; stage B1(a+2); vmcnt gate for tile b
  if (PRE) stage_half(BT, n0 + 128, k0 + 128, (char*)Bs, 1, wave, lane);
  QBAR1(); mma_quad<1, 0>(acc, aF, b0F);
  if (PRE) { asm volatile("s_waitcnt vmcnt(4)" ::: "memory"); }
  else     { asm volatile("s_waitcnt vmcnt(0)" ::: "memory"); }
  QBAR2();
  // P5: tile b (mq0,nq0); stage A1(a+2)
  ld_frag4(As, 2, wm * 64, quad, l16, aF);
  ld_frag2(Bs, 2, wn * 32, quad, l16, b0F);
  if (PRE) stage_half(xb, m0 + 128, k0 + 128, (char*)As, 1, wave, lane);
  QBAR1(); mma_quad<0, 0>(acc, aF, b0F); QBAR2();
  // P6: (mq0,nq1); stage B0(a+2)
  ld_frag2(Bs, 3, wn * 32, quad, l16, b1F);
  if (PRE) stage_half(BT, n0, k0 + 128, (char*)Bs, 0, wave, lane);
  QBAR1(); mma_quad<0, 1>(acc, aF, b1F); QBAR2();
  // P7: (mq1,nq1); stage A0(b+2)
  ld_frag4(As, 3, wm * 64, quad, l16, aF);
  if (PRE) stage_half(xb, m0, k0 + 192, (char*)As, 2, wave, lane);
  QBAR1(); mma_quad<1, 1>(acc, aF, b1F); QBAR2();
  // P8: (mq1,nq0); stage B1(b+2); vmcnt gate for tile a+2
  if (PRE) stage_half(BT, n0 + 128, k0 + 192, (char*)Bs, 3, wave, lane);
  QBAR1(); mma_quad<1, 0>(acc, aF, b0F);
  if (PRE) { asm volatile("s_waitcnt vmcnt(4)" ::: "memory"); }
  QBAR2();
}

__global__ __launch_bounds__(512) void qkv_gemm8(const bf16* __restrict__ xb,
                                                 const bf16* __restrict__ WT,
                                                 const float* __restrict__ bq,
                                                 const float* __restrict__ bk,
                                                 const float* __restrict__ bv,
                                                 bf16* __restrict__ Qd,
                                                 bf16* __restrict__ Kd,
                                                 bf16* __restrict__ Vd) {
  extern __shared__ char smem_raw[];
  bf16* As = (bf16*)smem_raw;            // 64 KiB
  bf16* Bs = (bf16*)(smem_raw + 65536);  // 64 KiB

  const int tid = threadIdx.x, lane = tid & 63, wave = tid >> 6;
  const int wm = wave >> 2, wn = wave & 3;
  const int quad = lane >> 4, l16 = lane & 15;
  // XCD chunk swizzle: 192 blocks, 24 consecutive logical tiles per XCD
  const int ob = (blockIdx.x & 7) * 24 + (blockIdx.x >> 3);
  const int m0 = (ob / 12) * 256, n0 = (ob % 12) * 256;

  f32x4 acc[8][4];
  const f32x4 zero = {0.f, 0.f, 0.f, 0.f};
#pragma unroll
  for (int i = 0; i < 8; ++i)
#pragma unroll
    for (int j = 0; j < 4; ++j) acc[i][j] = zero;

  // prologue: tile0 fully + A0,B1 of tile1 (12 gloads); vmcnt(4) -> tile0 ready
  stage_half(xb, m0, 0, (char*)As, 0, wave, lane);
  stage_half(WT, n0, 0, (char*)Bs, 0, wave, lane);
  stage_half(xb, m0 + 128, 0, (char*)As, 1, wave, lane);
  stage_half(WT, n0 + 128, 0, (char*)Bs, 1, wave, lane);
  stage_half(xb, m0, 64, (char*)As, 2, wave, lane);
  stage_half(WT, n0 + 128, 64, (char*)Bs, 3, wave, lane);
  asm volatile("s_waitcnt vmcnt(4)" ::: "memory");
  __builtin_amdgcn_s_barrier();

  for (int j = 0; j < 7; ++j)
    qkv_iter<true>(j * 128, xb, WT, m0, n0, As, Bs, acc, wave, lane, wm, wn, quad, l16);
  qkv_iter<false>(896, xb, WT, m0, n0, As, Bs, acc, wave, lane, wm, wn, quad, l16);

  // epilogue: bias, fold softmax scale into Q, scatter to [B,H,S,HD]
#pragma unroll
  for (int MQ = 0; MQ < 2; ++MQ)
#pragma unroll
    for (int mf = 0; mf < 4; ++mf)
#pragma unroll
      for (int NQ = 0; NQ < 2; ++NQ)
#pragma unroll
        for (int nf = 0; nf < 2; ++nf) {
          const int n = n0 + NQ * 128 + wn * 32 + nf * 16 + l16;  // 0..3071
          const int sel = n >> 10, d = n & 1023;
          const float bias = (sel == 0 ? bq : sel == 1 ? bk : bv)[d];
          bf16* dst = (sel == 0 ? Qd : sel == 1 ? Kd : Vd);
          const float scl = (sel == 0) ? 0.125f : 1.f;
          const int h = d >> 6, hd = d & 63;
#pragma unroll
          for (int r = 0; r < 4; ++r) {
            const int token = m0 + MQ * 128 + wm * 64 + mf * 16 + quad * 4 + r;
            const int bb = token >> 11, s = token & 2047;
            const float v = (acc[MQ * 4 + mf][NQ * 2 + nf][r] + bias) * scl;
            dst[((((size_t)bb * 16 + h) * 2048 + s) << 6) + hd] = (bf16)v;
          }
        }
}

// ---------------------------------------------------------------------------
// Shared GEMM mainloop (m97 structure) for out_gemm, templated on NJ.
// ---------------------------------------------------------------------------
template <int NJ>
__device__ __forceinline__ void gemm_mainloop(const bf16* __restrict__ A,
                                              const bf16* __restrict__ BT, int K,
                                              int m0, int n0, bf16* As, bf16* Bs,
                                              f32x4 (&acc)[4][NJ]) {
  constexpr int BN = NJ * 32;
  const int tid = threadIdx.x;
  const int lane = tid & 63;
  const int wave = tid >> 6;
  const int wm = wave >> 1, wn = wave & 1;
  const int quad = lane >> 4, l16 = lane & 15;

  const f32x4 zero = {0.f, 0.f, 0.f, 0.f};
#pragma unroll
  for (int i = 0; i < 4; ++i)
#pragma unroll
    for (int j = 0; j < NJ; ++j) acc[i][j] = zero;

  for (int k0 = 0; k0 < K; k0 += 32) {
#pragma unroll
    for (int c = 0; c < 2; ++c) {  // A: 512 chunks
      int chunk = wave * 128 + c * 64 + lane;
      int row = chunk >> 2;
      int cg = (chunk & 3) ^ ((row >> 1) & 3);
      ldsdma16(A + (size_t)(m0 + row) * K + k0 + cg * 8,
               (char*)As + (size_t)(wave * 128 + c * 64) * 16);
    }
#pragma unroll
    for (int c = 0; c < BN / 64; ++c) {  // B: BN*4 chunks
      int chunk = wave * (BN / 64) * 64 + c * 64 + lane;
      int row = chunk >> 2;
      int cg = (chunk & 3) ^ ((row >> 1) & 3);
      ldsdma16(BT + (size_t)(n0 + row) * K + k0 + cg * 8,
               (char*)Bs + (size_t)(wave * (BN / 64) * 64 + c * 64) * 16);
    }
    __syncthreads();
    bf16x8 af[4], bfv[NJ];
#pragma unroll
    for (int i = 0; i < 4; ++i) {
      int ra = wm * 64 + i * 16 + l16;
      af[i] = ((const bf16x8*)As)[ra * 4 + (quad ^ ((ra >> 1) & 3))];
    }
#pragma unroll
    for (int j = 0; j < NJ; ++j) {
      int rb = wn * (BN / 2) + j * 16 + l16;
      bfv[j] = ((const bf16x8*)Bs)[rb * 4 + (quad ^ ((rb >> 1) & 3))];
    }
#pragma unroll
    for (int i = 0; i < 4; ++i)
#pragma unroll
      for (int j = 0; j < NJ; ++j) acc[i][j] = MFMA16(af[i], bfv[j], acc[i][j]);
    __syncthreads();
  }
}

// ---------------------------------------------------------------------------
// Sliding-window attention. NEW (R11): Ks/Ps LDS UNION -> 34.8 KiB total ->
// 4 blocks/CU (was 3 at 50.9 KiB); launch_bounds(256,4) caps VGPR at 128.
// Union safety: within a phase the order is  K-DMA writes Ks -> syncthreads
// (drains DMA) -> QK reads Ks (each wave's reads consumed by its MFMAs) ->
// softmax (VALU) -> s_barrier (all waves done reading Ks) -> Ps writes onto
// the same region -> pa reads -> PV. Next phase's K-DMA comes after the
// phase-entry syncthreads, which orders it after all pa reads.
// ---------------------------------------------------------------------------
template <int NT, int MODE>
__device__ __forceinline__ void attn_phase(const int start, const bf16* __restrict__ Kb,
                                           const bf16* __restrict__ Vb, bf16* KsPs, bf16* Vt,
                                           const bf16x8 qa0, const bf16x8 qa1,
                                           const int i0, float (&mrow)[4], float (&lrow)[4],
                                           f32x4 (&oacc)[4]) {
  const int tid = threadIdx.x, lane = tid & 63, wave = tid >> 6;
  const int quad = lane >> 4, l16 = lane & 15;
  const f32x4 zero = {0.f, 0.f, 0.f, 0.f};

  __syncthreads();  // previous phase's Ks/Ps/Vt use done
#pragma unroll
  for (int c = 0; c < NT / 2; ++c) {
    int chunk = c * 256 + wave * 64 + lane;
    int row = chunk >> 3;
    int cg = (chunk & 7) ^ (row & 7);
    ldsdma16(Kb + (size_t)(start + row) * 64 + cg * 8,
             (char*)KsPs + (size_t)(c * 256 + wave * 64) * 16);
  }
  if (NT == 8) {
    const int key = tid >> 1, hc = (tid & 1) * 32;
    const bf16* vp = Vb + (size_t)(start + key) * 64 + hc;
    bf16x8 v0 = ((const bf16x8*)vp)[0], v1 = ((const bf16x8*)vp)[1];
    bf16x8 v2 = ((const bf16x8*)vp)[2], v3 = ((const bf16x8*)vp)[3];
#pragma unroll
    for (int i = 0; i < 8; ++i) Vt[(hc + i) * 136 + key] = v0[i];
#pragma unroll
    for (int i = 0; i < 8; ++i) Vt[(hc + 8 + i) * 136 + key] = v1[i];
#pragma unroll
    for (int i = 0; i < 8; ++i) Vt[(hc + 16 + i) * 136 + key] = v2[i];
#pragma unroll
    for (int i = 0; i < 8; ++i) Vt[(hc + 24 + i) * 136 + key] = v3[i];
  } else {
    const int key = tid >> 2, hc = (tid & 3) * 16;
    const bf16* vp = Vb + (size_t)(start + key) * 64 + hc;
    bf16x8 v0 = ((const bf16x8*)vp)[0], v1 = ((const bf16x8*)vp)[1];
#pragma unroll
    for (int i = 0; i < 8; ++i) Vt[(hc + i) * 136 + key] = v0[i];
#pragma unroll
    for (int i = 0; i < 8; ++i) Vt[(hc + 8 + i) * 136 + key] = v1[i];
  }
  __syncthreads();  // K-DMA + V stores landed

  // scores S = Q K^T from the Ks view of the union
  f32x4 sc[NT];
  __builtin_amdgcn_s_setprio(1);
#pragma unroll
  for (int nt = 0; nt < NT; ++nt) {
    int key = nt * 16 + l16;
    bf16x8 kb0 = ((const bf16x8*)KsPs)[key * 8 + ((0 * 4 + quad) ^ (key & 7))];
    bf16x8 kb1 = ((const bf16x8*)KsPs)[key * 8 + ((1 * 4 + quad) ^ (key & 7))];
    f32x4 s = zero;
    s = MFMA16(qa0, kb0, s);
    s = MFMA16(qa1, kb1, s);
    sc[nt] = s;
  }
  __builtin_amdgcn_s_setprio(0);

  // mask + online softmax (VALU; overlaps other waves' QK)
  float alpha[4];
#pragma unroll
  for (int r = 0; r < 4; ++r) {
    const int i = i0 + r;
    float mx = -1e30f;
#pragma unroll
    for (int nt = 0; nt < NT; ++nt) {
      float s = sc[nt][r];
      if (MODE == 1) {
        const bool valid = (start + nt * 16 + l16 + 255 >= i);
        s = valid ? s : -1e30f;
        sc[nt][r] = s;
      } else if (MODE == 2) {
        const bool valid = (start + nt * 16 + l16 <= i);
        s = valid ? s : -1e30f;
        sc[nt][r] = s;
      }
      mx = fmaxf(mx, s);
    }
#pragma unroll
    for (int m = 8; m >= 1; m >>= 1) mx = fmaxf(mx, __shfl_xor(mx, m, 64));
    const float mnew = fmaxf(mrow[r], mx);
    alpha[r] = __expf(mrow[r] - mnew);
    mrow[r] = mnew;
    float rs = 0.f;
#pragma unroll
    for (int nt = 0; nt < NT; ++nt) {
      const float p = __expf(sc[nt][r] - mnew);
      sc[nt][r] = p;
      rs += p;
    }
#pragma unroll
    for (int m = 8; m >= 1; m >>= 1) rs += __shfl_xor(rs, m, 64);
    lrow[r] = lrow[r] * alpha[r] + rs;
  }

  // all waves finished their Ks reads -> safe to overlay Ps on the union
  __builtin_amdgcn_s_barrier();

  bf16* Psw = KsPs + wave * (16 * 136);
#pragma unroll
  for (int nt = 0; nt < NT; ++nt)
#pragma unroll
    for (int r = 0; r < 4; ++r)
      Psw[(quad * 4 + r) * 136 + nt * 16 + l16] = (bf16)sc[nt][r];
  asm volatile("s_waitcnt lgkmcnt(0)" ::: "memory");  // same-wave LDS RAW
  bf16x8 pa[NT / 2];
#pragma unroll
  for (int ks = 0; ks < NT / 2; ++ks)
    pa[ks] = ((const bf16x8*)Psw)[l16 * 17 + ks * 4 + quad];

  __builtin_amdgcn_s_setprio(1);
#pragma unroll
  for (int ht = 0; ht < 4; ++ht) {
    f32x4 o = oacc[ht];
#pragma unroll
    for (int r = 0; r < 4; ++r) o[r] *= alpha[r];
#pragma unroll
    for (int ks = 0; ks < NT / 2; ++ks) {
      bf16x8 vb = ((const bf16x8*)Vt)[(ht * 16 + l16) * 17 + ks * 4 + quad];
      o = MFMA16(pa[ks], vb, o);
    }
    oacc[ht] = o;
  }
  __builtin_amdgcn_s_setprio(0);
}

__global__ __launch_bounds__(256, 4) void attn_kernel(const bf16* __restrict__ Q,
                                                      const bf16* __restrict__ K,
                                                      const bf16* __restrict__ V,
                                                      bf16* __restrict__ Ao) {
  // union region: Ks (128x64 = 16384 B) overlaid by Ps (4 waves x 16 x 136 =
  // 17408 B) -> 8704 bf16. Plus Vt. Total 34816 B -> 4 blocks/CU.
  __shared__ bf16 KsPs[8704] __attribute__((aligned(16)));
  __shared__ bf16 Vt[64 * 136] __attribute__((aligned(16)));

  const int tid = threadIdx.x, lane = tid & 63, wave = tid >> 6;
  const int quad = lane >> 4, l16 = lane & 15;
  // XCD chunk swizzle: 1024 blocks, 128 consecutive logical jobs per XCD
  const int ob = (blockIdx.x & 7) * 128 + (blockIdx.x >> 3);
  const int qt = ob & 31, h = (ob >> 5) & 15, b = ob >> 9;
  const int q0 = qt * 64;
  const size_t base = ((size_t)(b * 16 + h)) * 2048 * 64;
  const bf16* Qb = Q + base + (size_t)q0 * 64;
  const bf16* Kb = K + base;
  const bf16* Vb = V + base;

  const bf16* qrow = Qb + (size_t)(wave * 16 + l16) * 64 + quad * 8;
  const bf16x8 qa0 = *(const bf16x8*)qrow;
  const bf16x8 qa1 = *(const bf16x8*)(qrow + 32);

  float mrow[4], lrow[4];
  f32x4 oacc[4];
  const f32x4 zero = {0.f, 0.f, 0.f, 0.f};
#pragma unroll
  for (int r = 0; r < 4; ++r) { mrow[r] = -1e30f; lrow[r] = 0.f; }
#pragma unroll
  for (int t = 0; t < 4; ++t) oacc[t] = zero;

  const int i0 = q0 + wave * 16 + quad * 4;

  if (q0 >= 256)
    attn_phase<8, 1>(q0 - 256, Kb, Vb, KsPs, Vt, qa0, qa1, i0, mrow, lrow, oacc);
  else if (q0 == 192)
    attn_phase<4, 0>(0, Kb, Vb, KsPs, Vt, qa0, qa1, i0, mrow, lrow, oacc);
  if (q0 >= 128)
    attn_phase<8, 0>(q0 - 128, Kb, Vb, KsPs, Vt, qa0, qa1, i0, mrow, lrow, oacc);
  else if (q0 == 64)
    attn_phase<4, 0>(0, Kb, Vb, KsPs, Vt, qa0, qa1, i0, mrow, lrow, oacc);
  attn_phase<4, 2>(q0, Kb, Vb, KsPs, Vt, qa0, qa1, i0, mrow, lrow, oacc);

#pragma unroll
  for (int r = 0; r < 4; ++r) {
    const float inv = 1.f / lrow[r];
    const int row = q0 + wave * 16 + quad * 4 + r;
    const size_t outb = ((size_t)(b * 2048 + row)) * 1024 + h * 64;
#pragma unroll
    for (int ht = 0; ht < 4; ++ht)
      Ao[outb + ht * 16 + l16] = (bf16)(oacc[ht][r] * inv);
  }
}

// ---------------------------------------------------------------------------
// Output GEMM: Ao[4096,1024] @ Wo + bo -> fp32 out. BN=64 (512 blocks, 2/CU),
// XCD chunk swizzle. Unchanged from the 168.2us anchor.
// ---------------------------------------------------------------------------
__global__ __launch_bounds__(256) void out_gemm(const bf16* __restrict__ Ain,
                                                const bf16* __restrict__ WoT,
                                                const float* __restrict__ bo,
                                                float* __restrict__ out) {
  __shared__ bf16 As[128 * 32] __attribute__((aligned(16)));
  __shared__ bf16 Bs[64 * 32] __attribute__((aligned(16)));
  f32x4 acc[4][2];
  const int ob = (blockIdx.x & 7) * 64 + (blockIdx.x >> 3);
  const int m0 = (ob >> 4) * 128, n0 = (ob & 15) * 64;
  gemm_mainloop<2>(Ain, WoT, 1024, m0, n0, As, Bs, acc);

  const int lane = threadIdx.x & 63, wave = threadIdx.x >> 6;
  const int wm = wave >> 1, wn = wave & 1;
  const int quad = lane >> 4, l16 = lane & 15;
#pragma unroll
  for (int j = 0; j < 2; ++j) {
    const int n = n0 + wn * 32 + j * 16 + l16;
    const float bias = bo[n];
#pragma unroll
    for (int i = 0; i < 4; ++i) {
#pragma unroll
      for (int r = 0; r < 4; ++r) {
        const int token = m0 + wm * 64 + i * 16 + quad * 4 + r;
        out[(size_t)token * 1024 + n] = acc[i][j][r] + bias;
      }
    }
  }
}

// ---------------------------------------------------------------------------
extern "C" void kernel_launch(void* const* d_in, const int* in_sizes, int n_in,
                              void* d_out, int out_size, void* d_ws, size_t ws_size,
                              hipStream_t stream) {
  const float* x  = (const float*)d_in[0];
  const float* Wq = (const float*)d_in[1];
  const float* bq = (const float*)d_in[2];
  const float* Wk = (const float*)d_in[3];
  const float* bk = (const float*)d_in[4];
  const float* Wv = (const float*)d_in[5];
  const float* bv = (const float*)d_in[6];
  const float* Wo = (const float*)d_in[7];
  const float* bo = (const float*)d_in[8];
  float* out = (float*)d_out;

  char* ws = (char*)d_ws;
  bf16* xb = (bf16*)(ws);                      //  8 MB  x bf16
  bf16* WT = (bf16*)(ws + ((size_t)8 << 20));  //  8 MB  WqT|WkT|WvT|WoT bf16 [n][k]
  bf16* Qd = (bf16*)(ws + ((size_t)16 << 20)); //  8 MB  [B,H,S,HD]
  bf16* Kd = (bf16*)(ws + ((size_t)24 << 20)); //  8 MB
  bf16* Vd = (bf16*)(ws + ((size_t)32 << 20)); //  8 MB
  bf16* Ao = (bf16*)(ws + ((size_t)40 << 20)); //  8 MB  [B,S,DIM]

  (void)hipFuncSetAttribute((const void*)qkv_gemm8,
                            hipFuncAttributeMaxDynamicSharedMemorySize, 131072);

  prep_kernel<<<dim3(16, 16, 5), 256, 0, stream>>>(x, Wq, Wk, Wv, Wo, xb, WT);
  qkv_gemm8<<<dim3(192), 512, 131072, stream>>>(xb, WT, bq, bk, bv, Qd, Kd, Vd);
  attn_kernel<<<dim3(1024), 256, 0, stream>>>(Qd, Kd, Vd, Ao);
  out_gemm<<<dim3(512), 256, 0, stream>>>(Ao, WT + (size_t)3 * 1024 * 1024, bo, out);
}